// Round 1
// baseline (588.939 us; speedup 1.0000x reference)
//
#include <hip/hip_runtime.h>
#include <hip/hip_cooperative_groups.h>

namespace cg = cooperative_groups;

#define G 4096
#define BROWS 8192
#define NBLK 1024
#define NTHR 256
#define PAIR_BLOCKS 16384  // virtual pair-block count (layout preserved from 4-kernel version)

typedef float f4 __attribute__((ext_vector_type(4)));

// ws float offsets (unchanged layout)
#define OFF_PART 0                      // part[256][4096] = 1048576 floats (4 MiB)
#define OFF_VMAG 1048576                // 4096 floats
#define OFF_PT   1052672                // 16384 floats
#define OFF_PN   1069056                // 16384 ints

// ---------------------------------------------------------------------------
// Fused cooperative kernel: P1 -> grid.sync -> P2 -> grid.sync -> P3 ->
// grid.sync -> P4. All arithmetic is bitwise-identical to the 4-kernel
// version (same summation orders, same partial layouts).
// 1024 blocks x 256 thr, <=128 VGPR (launch_bounds) => 4 blocks/CU resident.
// ---------------------------------------------------------------------------
__global__ __launch_bounds__(NTHR, 4) void fused_all(const float* __restrict__ vel,
                                                     const float* __restrict__ adj,
                                                     float* __restrict__ ws,
                                                     float* __restrict__ out) {
    float* part = ws + OFF_PART;
    float* vmag = ws + OFF_VMAG;
    float* pt   = ws + OFF_PT;
    int*   pn   = (int*)(ws + OFF_PN);

    const int tid = threadIdx.x;
    const int bid = blockIdx.x;

    // ---- Phase 1: per-32-row-stripe |velocity| column sums (== vmag_partial)
    {
        const int col0 = (bid & 3) * 1024 + tid * 4;
        const int stripe = bid >> 2;
        const float* p = vel + (size_t)stripe * 32 * G + col0;
        float ax = 0.f, ay = 0.f, az = 0.f, aw = 0.f;
#pragma unroll 8
        for (int r = 0; r < 32; ++r) {
            f4 v = *(const f4*)p;
            ax += fabsf(v.x); ay += fabsf(v.y); az += fabsf(v.z); aw += fabsf(v.w);
            p += G;
        }
        f4 o = {ax, ay, az, aw};
        *(f4*)(part + (size_t)stripe * G + col0) = o;
    }
    cg::this_grid().sync();

    // ---- Phase 2: stripe reduction -> vmag (== vmag_reduce, blocks 0..31)
    __shared__ f4 red[NTHR];
    if (bid < 32) {
        const int c4 = tid & 31;
        const int s0 = tid >> 5;
        const int col0 = bid * 128 + c4 * 4;
        f4 acc = {0.f, 0.f, 0.f, 0.f};
#pragma unroll
        for (int k = 0; k < 32; ++k)
            acc += *(const f4*)(part + (size_t)(s0 + 8 * k) * G + col0);
        red[tid] = acc;
        __syncthreads();
#pragma unroll
        for (int off = 128; off >= 32; off >>= 1) {
            if (tid < off) red[tid] += red[tid + off];
            __syncthreads();
        }
        if (tid < 32) {
            f4 a = red[tid] * (1.0f / (float)BROWS);
            *(f4*)(vmag + bid * 128 + tid * 4) = a;
        }
    }
    cg::this_grid().sync();

    // ---- Phase 3: pairwise pass. 16 virtual pair-blocks per real block.
    // Branchless but bit-exact: contrib = |vj - a*vi| * a^2 ; n += a^2.
    // (a in {-1,0,1}: a=1 -> |vj-vi|; a=-1 -> vj+vi (>=0, fabs no-op);
    //  a=0 -> t+0. fmaf with a in {-1,0,1} rounds identically.)
    __shared__ float st[4];
    __shared__ float snf[4];
    {
        f4 vjq[4];
#pragma unroll
        for (int q = 0; q < 4; ++q) vjq[q] = *(const f4*)(vmag + q * 1024 + tid * 4);
        const f4 vis = *(const f4*)(vmag + bid * 4);  // 4 TF rows this block touches
        const float* ablk = adj + (size_t)bid * 16384;
        const int wave = tid >> 6;

        for (int sub = 0; sub < 16; ++sub) {
            const int vb = bid * 16 + sub;            // virtual pair-block id
            const f4 a = *(const f4*)(ablk + sub * 1024 + tid * 4);
            const float vi = vis[sub >> 2];
            const f4 vj = vjq[sub & 3];

            float t = 0.f, nf = 0.f;
            float a2;
            a2 = a.x * a.x; t = fmaf(fabsf(fmaf(a.x, -vi, vj.x)), a2, t); nf += a2;
            a2 = a.y * a.y; t = fmaf(fabsf(fmaf(a.y, -vi, vj.y)), a2, t); nf += a2;
            a2 = a.z * a.z; t = fmaf(fabsf(fmaf(a.z, -vi, vj.z)), a2, t); nf += a2;
            a2 = a.w * a.w; t = fmaf(fabsf(fmaf(a.w, -vi, vj.w)), a2, t); nf += a2;

#pragma unroll
            for (int off = 32; off > 0; off >>= 1) {
                t  += __shfl_down(t, off);
                nf += __shfl_down(nf, off);
            }
            if ((tid & 63) == 0) { st[wave] = t; snf[wave] = nf; }
            __syncthreads();
            if (tid == 0) {
                pt[vb] = st[0] + st[1] + st[2] + st[3];
                pn[vb] = (int)(snf[0] + snf[1] + snf[2] + snf[3]);  // exact (<=1024)
            }
            __syncthreads();  // protect st/snf before next sub
        }
    }
    cg::this_grid().sync();

    // ---- Phase 4: block 0 replays finalize_big's 1024-thread reduction with
    // 4 roles/thread; wave-tree and final-sum orders are bitwise identical.
    if (bid == 0) {
        __shared__ float fst[16];
        __shared__ int   fsn[16];
        float tv[4];
        int   nv[4];
#pragma unroll
        for (int r = 0; r < 4; ++r) {
            const int u = tid + r * 256;  // original thread id in [0,1024)
            float t = 0.f;
            int n = 0;
#pragma unroll
            for (int k = 0; k < 16; ++k) {
                t += pt[u + k * 1024];
                n += pn[u + k * 1024];
            }
#pragma unroll
            for (int off = 32; off > 0; off >>= 1) {
                t += __shfl_down(t, off);
                n += __shfl_down(n, off);
            }
            tv[r] = t;
            nv[r] = n;
        }
        const int wave = tid >> 6;
        if ((tid & 63) == 0) {
#pragma unroll
            for (int r = 0; r < 4; ++r) { fst[wave + r * 4] = tv[r]; fsn[wave + r * 4] = nv[r]; }
        }
        __syncthreads();
        if (tid == 0) {
            float tt = 0.f;
            int nn = 0;
#pragma unroll
            for (int k = 0; k < 16; ++k) { tt += fst[k]; nn += fsn[k]; }
            out[0] = (nn > 0) ? (tt / fmaxf((float)nn, 1.f)) : 0.f;
        }
    }
}

// ---------------------------------------------------------------------------
// Fallback path: the proven 4-kernel pipeline (verbatim from prior version),
// used only if cooperative launch is rejected (e.g. by graph capture).
// ---------------------------------------------------------------------------
__global__ __launch_bounds__(256) void vmag_partial(const float* __restrict__ vel,
                                                    float* __restrict__ part) {
    const int col0 = (blockIdx.x & 3) * 1024 + threadIdx.x * 4;
    const int stripe = blockIdx.x >> 2;
    const float* p = vel + (size_t)stripe * 32 * G + col0;
    float ax = 0.f, ay = 0.f, az = 0.f, aw = 0.f;
#pragma unroll 8
    for (int r = 0; r < 32; ++r) {
        f4 v = *(const f4*)p;
        ax += fabsf(v.x); ay += fabsf(v.y); az += fabsf(v.z); aw += fabsf(v.w);
        p += G;
    }
    f4 o = {ax, ay, az, aw};
    *(f4*)(part + (size_t)stripe * G + col0) = o;
}

__global__ __launch_bounds__(256) void vmag_reduce(const float* __restrict__ part,
                                                   float* __restrict__ vmag) {
    __shared__ f4 red[256];
    const int t = threadIdx.x;
    const int c4 = t & 31;
    const int s0 = t >> 5;
    const int col0 = blockIdx.x * 128 + c4 * 4;
    f4 acc = {0.f, 0.f, 0.f, 0.f};
#pragma unroll
    for (int k = 0; k < 32; ++k)
        acc += *(const f4*)(part + (size_t)(s0 + 8 * k) * G + col0);
    red[t] = acc;
    __syncthreads();
#pragma unroll
    for (int off = 128; off >= 32; off >>= 1) {
        if (t < off) red[t] += red[t + off];
        __syncthreads();
    }
    if (t < 32) {
        f4 a = red[t] * (1.0f / (float)BROWS);
        *(f4*)(vmag + blockIdx.x * 128 + t * 4) = a;
    }
}

__global__ __launch_bounds__(256) void pair_kernel(const float* __restrict__ adj,
                                                   const float* __restrict__ vmag,
                                                   float* __restrict__ pt,
                                                   int* __restrict__ pn) {
    const size_t e = ((size_t)blockIdx.x * 256 + threadIdx.x) * 4;
    const int i = (int)(e >> 12);
    const int j = (int)(e & 4095);
    const f4 a = *(const f4*)(adj + e);
    const float vi = vmag[i];
    const f4 vj = *(const f4*)(vmag + j);

    float t = 0.f;
    int n = 0;
    if (a.x != 0.f) { t += (a.x > 0.f) ? fabsf(vj.x - vi) : (vj.x + vi); ++n; }
    if (a.y != 0.f) { t += (a.y > 0.f) ? fabsf(vj.y - vi) : (vj.y + vi); ++n; }
    if (a.z != 0.f) { t += (a.z > 0.f) ? fabsf(vj.z - vi) : (vj.z + vi); ++n; }
    if (a.w != 0.f) { t += (a.w > 0.f) ? fabsf(vj.w - vi) : (vj.w + vi); ++n; }

#pragma unroll
    for (int off = 32; off > 0; off >>= 1) {
        t += __shfl_down(t, off);
        n += __shfl_down(n, off);
    }
    __shared__ float st[4];
    __shared__ int sn[4];
    const int wave = threadIdx.x >> 6;
    if ((threadIdx.x & 63) == 0) { st[wave] = t; sn[wave] = n; }
    __syncthreads();
    if (threadIdx.x == 0) {
        pt[blockIdx.x] = st[0] + st[1] + st[2] + st[3];
        pn[blockIdx.x] = sn[0] + sn[1] + sn[2] + sn[3];
    }
}

__global__ __launch_bounds__(1024) void finalize_big(const float* __restrict__ pt,
                                                     const int* __restrict__ pn,
                                                     float* __restrict__ out) {
    float t = 0.f;
    int n = 0;
#pragma unroll
    for (int k = 0; k < PAIR_BLOCKS / 1024; ++k) {
        t += pt[threadIdx.x + k * 1024];
        n += pn[threadIdx.x + k * 1024];
    }
#pragma unroll
    for (int off = 32; off > 0; off >>= 1) {
        t += __shfl_down(t, off);
        n += __shfl_down(n, off);
    }
    __shared__ float st[16];
    __shared__ int sn[16];
    const int wave = threadIdx.x >> 6;
    if ((threadIdx.x & 63) == 0) { st[wave] = t; sn[wave] = n; }
    __syncthreads();
    if (threadIdx.x == 0) {
        float tt = 0.f;
        int nn = 0;
#pragma unroll
        for (int k = 0; k < 16; ++k) { tt += st[k]; nn += sn[k]; }
        out[0] = (nn > 0) ? (tt / fmaxf((float)nn, 1.f)) : 0.f;
    }
}

extern "C" void kernel_launch(void* const* d_in, const int* in_sizes, int n_in,
                              void* d_out, int out_size, void* d_ws, size_t ws_size,
                              hipStream_t stream) {
    const float* vel = (const float*)d_in[0];
    // d_in[1] (perturbation_idx) unused by the reference.
    const float* adj = (const float*)d_in[2];
    float* wsf = (float*)d_ws;
    float* out = (float*)d_out;

    void* args[] = {(void*)&vel, (void*)&adj, (void*)&wsf, (void*)&out};
    hipError_t err = hipLaunchCooperativeKernel(fused_all, dim3(NBLK), dim3(NTHR),
                                                args, 0u, stream);
    if (err != hipSuccess) {
        // Cooperative launch unavailable (e.g. under this capture mode):
        // fall back to the proven 4-kernel pipeline (bitwise-identical output).
        float* part = wsf + OFF_PART;
        float* vmag = wsf + OFF_VMAG;
        float* pt   = wsf + OFF_PT;
        int*   pn   = (int*)(wsf + OFF_PN);
        vmag_partial<<<1024, 256, 0, stream>>>(vel, part);
        vmag_reduce<<<32, 256, 0, stream>>>(part, vmag);
        pair_kernel<<<PAIR_BLOCKS, 256, 0, stream>>>(adj, vmag, pt, pn);
        finalize_big<<<1, 1024, 0, stream>>>(pt, pn, out);
    }
}

// Round 2
// 238.028 us; speedup vs baseline: 2.4742x; 2.4742x over previous
//
#include <hip/hip_runtime.h>

#define G 4096
#define BROWS 8192
#define STRIPES 256        // 8192 rows / 32 rows per stripe
#define P3_BLOCKS 1024     // pairwise: 1 block per 4 adj rows (64 KB contiguous)

typedef float f4 __attribute__((ext_vector_type(4)));

// ws float offsets
#define OFF_PART 0                      // part[256][4096] = 1048576 floats (4 MiB)
#define OFF_VMAG 1048576                // 4096 floats
#define OFF_PT   1052672                // 1024 floats
#define OFF_PN   1069056                // 1024 ints

// P1: per-32-row-stripe |velocity| column sums. 1024 blocks -> 16 waves/CU.
// (unchanged from the proven 237 µs version)
__global__ __launch_bounds__(256) void vmag_partial(const float* __restrict__ vel,
                                                    float* __restrict__ part) {
    const int col0 = (blockIdx.x & 3) * 1024 + threadIdx.x * 4;
    const int stripe = blockIdx.x >> 2;
    const float* p = vel + (size_t)stripe * 32 * G + col0;
    float ax = 0.f, ay = 0.f, az = 0.f, aw = 0.f;
#pragma unroll 8
    for (int r = 0; r < 32; ++r) {
        f4 v = *(const f4*)p;
        ax += fabsf(v.x); ay += fabsf(v.y); az += fabsf(v.z); aw += fabsf(v.w);
        p += G;
    }
    f4 o = {ax, ay, az, aw};
    *(f4*)(part + (size_t)stripe * G + col0) = o;  // plain store, no atomics
}

// P2: 32 blocks; block b reduces cols [b*128, b*128+128) over 256 stripes.
// (unchanged)
__global__ __launch_bounds__(256) void vmag_reduce(const float* __restrict__ part,
                                                   float* __restrict__ vmag) {
    __shared__ f4 red[256];
    const int t = threadIdx.x;
    const int c4 = t & 31;
    const int s0 = t >> 5;
    const int col0 = blockIdx.x * 128 + c4 * 4;
    f4 acc = {0.f, 0.f, 0.f, 0.f};
#pragma unroll
    for (int k = 0; k < 32; ++k)
        acc += *(const f4*)(part + (size_t)(s0 + 8 * k) * G + col0);
    red[t] = acc;  // red[s0*32 + c4]
    __syncthreads();
#pragma unroll
    for (int off = 128; off >= 32; off >>= 1) {
        if (t < off) red[t] += red[t + off];
        __syncthreads();
    }
    if (t < 32) {
        f4 a = red[t] * (1.0f / (float)BROWS);
        *(f4*)(vmag + blockIdx.x * 128 + t * 4) = a;
    }
}

// P3: pairwise pass, rewritten. 1024 blocks; block b owns adj rows 4b..4b+3
// (64 KB contiguous). Each thread accumulates 16 f4s in registers, then ONE
// shuffle+LDS reduction per block (amortized 16x vs old 16384-block version).
// Branchless, bit-exact element math: a in {-1,0,1}:
//   contrib = |vj - a*vi| * a^2 ; n += a^2
//   a=+1 -> |vj-vi|; a=-1 -> vj+vi (>=0, fabs is a no-op); a=0 -> +0.
__global__ __launch_bounds__(256) void pair_kernel(const float* __restrict__ adj,
                                                   const float* __restrict__ vmag,
                                                   float* __restrict__ pt,
                                                   int* __restrict__ pn) {
    const int tid = threadIdx.x;
    const int bid = blockIdx.x;

    // vj for the 4 column chunks this thread touches (col = q*1024 + tid*4)
    f4 vjq[4];
#pragma unroll
    for (int q = 0; q < 4; ++q) vjq[q] = *(const f4*)(vmag + q * 1024 + tid * 4);
    const f4 vis = *(const f4*)(vmag + bid * 4);  // vi for rows 4b..4b+3

    const float* ablk = adj + (size_t)bid * 16384;
    float t = 0.f, nf = 0.f;
#pragma unroll
    for (int sub = 0; sub < 16; ++sub) {
        const f4 a = *(const f4*)(ablk + sub * 1024 + tid * 4);
        const float vi = vis[sub >> 2];
        const f4 vj = vjq[sub & 3];
        float a2;
        a2 = a.x * a.x; t = fmaf(fabsf(fmaf(a.x, -vi, vj.x)), a2, t); nf += a2;
        a2 = a.y * a.y; t = fmaf(fabsf(fmaf(a.y, -vi, vj.y)), a2, t); nf += a2;
        a2 = a.z * a.z; t = fmaf(fabsf(fmaf(a.z, -vi, vj.z)), a2, t); nf += a2;
        a2 = a.w * a.w; t = fmaf(fabsf(fmaf(a.w, -vi, vj.w)), a2, t); nf += a2;
    }

#pragma unroll
    for (int off = 32; off > 0; off >>= 1) {
        t  += __shfl_down(t, off);
        nf += __shfl_down(nf, off);
    }
    __shared__ float st[4];
    __shared__ float snf[4];
    const int wave = tid >> 6;
    if ((tid & 63) == 0) { st[wave] = t; snf[wave] = nf; }
    __syncthreads();
    if (tid == 0) {
        pt[bid] = st[0] + st[1] + st[2] + st[3];
        pn[bid] = (int)(snf[0] + snf[1] + snf[2] + snf[3]);  // exact: <= 16384
    }
}

// P4: one 256-thread block reduces the 1024 partials.
__global__ __launch_bounds__(256) void finalize(const float* __restrict__ pt,
                                                const int* __restrict__ pn,
                                                float* __restrict__ out) {
    const int tid = threadIdx.x;
    float t = 0.f;
    int n = 0;
#pragma unroll
    for (int k = 0; k < 4; ++k) {
        t += pt[tid + k * 256];
        n += pn[tid + k * 256];
    }
#pragma unroll
    for (int off = 32; off > 0; off >>= 1) {
        t += __shfl_down(t, off);
        n += __shfl_down(n, off);
    }
    __shared__ float st[4];
    __shared__ int sn[4];
    const int wave = tid >> 6;
    if ((tid & 63) == 0) { st[wave] = t; sn[wave] = n; }
    __syncthreads();
    if (tid == 0) {
        float tt = st[0] + st[1] + st[2] + st[3];
        int nn = sn[0] + sn[1] + sn[2] + sn[3];
        out[0] = (nn > 0) ? (tt / fmaxf((float)nn, 1.f)) : 0.f;
    }
}

extern "C" void kernel_launch(void* const* d_in, const int* in_sizes, int n_in,
                              void* d_out, int out_size, void* d_ws, size_t ws_size,
                              hipStream_t stream) {
    const float* vel = (const float*)d_in[0];
    // d_in[1] (perturbation_idx) unused by the reference.
    const float* adj = (const float*)d_in[2];
    float* wsf = (float*)d_ws;
    float* part = wsf + OFF_PART;
    float* vmag = wsf + OFF_VMAG;
    float* pt   = wsf + OFF_PT;
    int*   pn   = (int*)(wsf + OFF_PN);
    float* out  = (float*)d_out;

    vmag_partial<<<1024, 256, 0, stream>>>(vel, part);
    vmag_reduce<<<32, 256, 0, stream>>>(part, vmag);
    pair_kernel<<<P3_BLOCKS, 256, 0, stream>>>(adj, vmag, pt, pn);
    finalize<<<1, 256, 0, stream>>>(pt, pn, out);
}